// Round 1
// baseline (230.013 us; speedup 1.0000x reference)
//
#include <hip/hip_runtime.h>
#include <math.h>

// ---------------- constants ----------------
static constexpr float TEMP_INV   = 1.0f / 0.07f;
static constexpr float C_MARGIN   = 0.5f;
static constexpr float T_MARGIN   = 1.0f;
static constexpr float ALPHA      = 0.25f;
static constexpr float SMOOTHING  = 0.1f;

// Gram GEMM tiling
static constexpr int GT   = 128;       // output tile (M=N)
static constexpr int GKT  = 16;        // K tile
static constexpr int GSTR = GKT + 4;   // LDS row stride (floats); 20*4=80B -> rows 16B aligned

// ---------------- init accumulators ----------------
__global__ __launch_bounds__(64) void init_accum_kernel(float* accum) {
    if (threadIdx.x < 16) accum[threadIdx.x] = 0.0f;
}

// ---------------- Gram matrix: G = F * F^T (fp32 vector) ----------------
__global__ __launch_bounds__(256) void gram_kernel(
    const float* __restrict__ F, float* __restrict__ G, int B, int D) {
    __shared__ float As[GT][GSTR];
    __shared__ float Bs[GT][GSTR];
    const int tid = threadIdx.x;
    const int tx = tid & 15, ty = tid >> 4;
    const int rowBase = blockIdx.y * GT;
    const int colBase = blockIdx.x * GT;

    float acc[8][8];
#pragma unroll
    for (int m = 0; m < 8; ++m)
#pragma unroll
        for (int n = 0; n < 8; ++n) acc[m][n] = 0.0f;

    for (int k0 = 0; k0 < D; k0 += GKT) {
        // stage 128 rows x 16 k for both tiles; 2 float4 per thread per tile
#pragma unroll
        for (int l = 0; l < 2; ++l) {
            int idx4 = l * 256 + tid;          // 0..511
            int r    = idx4 >> 2;              // 0..127
            int kq   = (idx4 & 3) << 2;        // 0,4,8,12
            float4 av = *(const float4*)(F + (size_t)(rowBase + r) * D + k0 + kq);
            float4 bv = *(const float4*)(F + (size_t)(colBase + r) * D + k0 + kq);
            *(float4*)(&As[r][kq]) = av;
            *(float4*)(&Bs[r][kq]) = bv;
        }
        __syncthreads();
#pragma unroll
        for (int kk = 0; kk < GKT; ++kk) {
            float a[8], b[8];
#pragma unroll
            for (int m = 0; m < 8; ++m) a[m] = As[ty + 16 * m][kk];
#pragma unroll
            for (int n = 0; n < 8; ++n) b[n] = Bs[tx + 16 * n][kk];
#pragma unroll
            for (int m = 0; m < 8; ++m)
#pragma unroll
                for (int n = 0; n < 8; ++n)
                    acc[m][n] = fmaf(a[m], b[n], acc[m][n]);
        }
        __syncthreads();
    }
#pragma unroll
    for (int m = 0; m < 8; ++m) {
        size_t rowOff = (size_t)(rowBase + ty + 16 * m) * B + colBase + tx;
#pragma unroll
        for (int n = 0; n < 8; ++n)
            G[rowOff + 16 * n] = acc[m][n];
    }
}

// ---------------- diagonal + inverse norms ----------------
__global__ __launch_bounds__(256) void diag_kernel(
    const float* __restrict__ G, float* __restrict__ diag,
    float* __restrict__ inv_norm, int B) {
    int j = blockIdx.x * 256 + threadIdx.x;
    if (j < B) {
        float r = G[(size_t)j * B + j];
        diag[j] = r;
        inv_norm[j] = 1.0f / sqrtf(r);
    }
}

// ---------------- per-row contrastive + triplet ----------------
__global__ __launch_bounds__(256) void row_loss_kernel(
    const float* __restrict__ G, const float* __restrict__ diag,
    const float* __restrict__ inv_norm, const int* __restrict__ labels,
    float* __restrict__ accum, int B) {
    extern __shared__ float smem[];
    float* d_row = smem;           // B floats
    float* p_d   = smem + B;       // up to 128 matched distances
    float* red   = p_d + 128;      // 12 reduction slots
    __shared__ int p_cnt;

    const int tid = threadIdx.x;
    const int i = blockIdx.x;
    if (tid == 0) p_cnt = 0;
    __syncthreads();

    const int   li     = labels[i];
    const float ri     = diag[i];
    const float inv_ni = inv_norm[i];
    const float* Grow  = G + (size_t)i * B;
    const float NEG0   = -logf(1.0f + 1e-8f);   // pos_loss for unmatched (pos=0)

    float pos_acc = 0.0f, neg_acc = 0.0f;
    for (int j = tid; j < B; j += 256) {
        float g   = Grow[j];
        float sim = g * inv_ni * inv_norm[j];
        float d2  = ri - 2.0f * g + diag[j];
        float d   = (d2 > 0.0f) ? sqrtf(d2) : 0.0f;
        if (labels[j] == li) {
            pos_acc += -logf(expf(sim * TEMP_INV) + 1e-8f);
            neg_acc += C_MARGIN;                 // relu(0.5 - 0)
            int slot = atomicAdd(&p_cnt, 1);
            if (slot < 128) p_d[slot] = d;
            d_row[j] = -1.0f;                    // sentinel: matched -> excluded as negative
        } else {
            pos_acc += NEG0;
            neg_acc += fmaxf(C_MARGIN - sim, 0.0f);
            d_row[j] = d;
        }
    }
    __syncthreads();

    const int cnt = (p_cnt < 128) ? p_cnt : 128;
    float trip_acc = 0.0f;
    for (int n = tid; n < B; n += 256) {
        float dn = d_row[n];
        if (dn >= 0.0f) {
            for (int p = 0; p < cnt; ++p)
                trip_acc += fmaxf(p_d[p] - dn + T_MARGIN, 0.0f);
        }
    }

    // block reduction of 3 partials
    float r0 = pos_acc, r1 = neg_acc, r2 = trip_acc;
#pragma unroll
    for (int off = 32; off > 0; off >>= 1) {
        r0 += __shfl_down(r0, off, 64);
        r1 += __shfl_down(r1, off, 64);
        r2 += __shfl_down(r2, off, 64);
    }
    int lane = tid & 63, wid = tid >> 6;
    if (lane == 0) { red[wid] = r0; red[4 + wid] = r1; red[8 + wid] = r2; }
    __syncthreads();
    if (tid == 0) {
        atomicAdd(&accum[0], red[0] + red[1] + red[2] + red[3]);
        atomicAdd(&accum[1], red[4] + red[5] + red[6] + red[7]);
        atomicAdd(&accum[2], red[8] + red[9] + red[10] + red[11]);
    }
}

// ---------------- focal + label smoothing (one block per row) ----------------
__global__ __launch_bounds__(256) void ce_kernel(
    const float* __restrict__ pred, const int* __restrict__ target,
    float* __restrict__ accum, int C, float off_const) {
    __shared__ float red[12];
    const int i = blockIdx.x;
    const int tid = threadIdx.x;
    const float* row = pred + (size_t)i * C;

    float m = -INFINITY;
    for (int j = tid; j < C; j += 256) m = fmaxf(m, row[j]);
#pragma unroll
    for (int off = 32; off > 0; off >>= 1) m = fmaxf(m, __shfl_down(m, off, 64));
    if ((tid & 63) == 0) red[tid >> 6] = m;
    __syncthreads();
    m = fmaxf(fmaxf(red[0], red[1]), fmaxf(red[2], red[3]));

    float se = 0.0f, sp = 0.0f;
    for (int j = tid; j < C; j += 256) {
        float v = row[j];
        se += expf(v - m);
        sp += v;
    }
#pragma unroll
    for (int off = 32; off > 0; off >>= 1) {
        se += __shfl_down(se, off, 64);
        sp += __shfl_down(sp, off, 64);
    }
    if ((tid & 63) == 0) { red[4 + (tid >> 6)] = se; red[8 + (tid >> 6)] = sp; }
    __syncthreads();
    if (tid == 0) {
        float seT = red[4] + red[5] + red[6] + red[7];
        float spT = red[8] + red[9] + red[10] + red[11];
        float lse = m + logf(seT);
        float tl  = row[target[i]] - lse;       // target log-prob
        float ce  = -tl;
        float pt  = expf(tl);
        float omp = 1.0f - pt;
        float focal = ALPHA * omp * omp * ce;   // gamma = 2
        float sumlogp = spT - (float)C * lse;
        float lsv = -(off_const * sumlogp + ((1.0f - SMOOTHING) - off_const) * tl);
        atomicAdd(&accum[3], focal);
        atomicAdd(&accum[4], lsv);
    }
}

// ---------------- combine ----------------
__global__ void combine_kernel(const float* __restrict__ accum,
                               float* __restrict__ out, int B) {
    if (threadIdx.x == 0 && blockIdx.x == 0) {
        double invB2 = 1.0 / ((double)B * (double)B);
        float lc = (float)(((double)accum[0] + (double)accum[1]) * invB2);
        float lt = (float)((double)accum[2] / ((double)B + 1e-8));
        float lf = accum[3] / (float)B;
        float ls = accum[4] / (float)B;
        out[0] = lc;
        out[1] = lt;
        out[2] = lf;
        out[3] = ls;
        out[4] = 0.1f * lc + 0.1f * lt + 0.4f * lf + 0.4f * ls;
    }
}

// ---------------- launch ----------------
extern "C" void kernel_launch(void* const* d_in, const int* in_sizes, int n_in,
                              void* d_out, int out_size, void* d_ws, size_t ws_size,
                              hipStream_t stream) {
    const float* pred     = (const float*)d_in[0];
    const int*   target   = (const int*)d_in[1];
    const float* features = (const float*)d_in[2];
    const int B = in_sizes[1];
    const int C = in_sizes[0] / B;
    const int D = in_sizes[2] / B;
    float* out = (float*)d_out;

    // workspace layout
    float* accum    = (float*)d_ws;        // 16 floats (64 B, padded to 256 B)
    float* diag     = accum + 64;          // B floats
    float* inv_norm = diag + B;            // B floats
    float* G        = inv_norm + B;        // B*B floats (~16.8 MB)

    init_accum_kernel<<<1, 64, 0, stream>>>(accum);

    dim3 ggrid(B / GT, B / GT);
    gram_kernel<<<ggrid, 256, 0, stream>>>(features, G, B, D);

    diag_kernel<<<(B + 255) / 256, 256, 0, stream>>>(G, diag, inv_norm, B);

    size_t sh = (size_t)B * sizeof(float) + 128 * sizeof(float) + 16 * sizeof(float);
    row_loss_kernel<<<B, 256, sh, stream>>>(G, diag, inv_norm, target, accum, B);

    float off_const = SMOOTHING / (float)(C - 1);
    ce_kernel<<<B, 256, 0, stream>>>(pred, target, accum, C, off_const);

    combine_kernel<<<1, 1, 0, stream>>>(accum, out, B);
}

// Round 2
// 169.188 us; speedup vs baseline: 1.3595x; 1.3595x over previous
//
#include <hip/hip_runtime.h>
#include <hip/hip_bf16.h>
#include <math.h>

typedef __attribute__((ext_vector_type(8))) short bf16x8;
typedef __attribute__((ext_vector_type(4))) float f32x4;

static constexpr float TEMP_INV  = 1.0f / 0.07f;
static constexpr float C_MARGIN  = 0.5f;
static constexpr float T_MARGIN  = 1.0f;
static constexpr float ALPHA     = 0.25f;
static constexpr float SMOOTHING = 0.1f;

__device__ __forceinline__ void gload_lds16(const void* g, void* l) {
    __builtin_amdgcn_global_load_lds(
        (const __attribute__((address_space(1))) void*)g,
        (__attribute__((address_space(3))) void*)l,
        16, 0, 0);
}

__device__ __forceinline__ unsigned short f2bf(float x) {
    __hip_bfloat16 h = __float2bfloat16(x);   // RNE
    return *reinterpret_cast<unsigned short*>(&h);
}
__device__ __forceinline__ float bf2f(unsigned short u) {
    union { unsigned int u32; float f; } U;
    U.u32 = ((unsigned int)u) << 16;
    return U.f;
}

// ---------------- init accumulators ----------------
__global__ __launch_bounds__(64) void init_accum_kernel(float* accum) {
    if (threadIdx.x < 16) accum[threadIdx.x] = 0.0f;
}

// ---------------- F (fp32) -> Fb (bf16) ----------------
__global__ __launch_bounds__(256) void cvt_kernel(
    const float* __restrict__ F, unsigned short* __restrict__ Fb, int n4) {
    int idx = blockIdx.x * 256 + threadIdx.x;
    if (idx < n4) {
        float4 v = ((const float4*)F)[idx];
        ushort4 o;
        o.x = f2bf(v.x); o.y = f2bf(v.y); o.z = f2bf(v.z); o.w = f2bf(v.w);
        ((ushort4*)Fb)[idx] = o;
    }
}

// ---------------- exact fp32 row norms (one wave per row) ----------------
__global__ __launch_bounds__(256) void norms_kernel(
    const float* __restrict__ F, float* __restrict__ diag,
    float* __restrict__ inv_norm, int D) {
    const int row  = blockIdx.x * 4 + (threadIdx.x >> 6);
    const int lane = threadIdx.x & 63;
    const float4* Fr = (const float4*)(F + (size_t)row * D);
    const int n4 = D >> 2;
    float s = 0.0f;
    for (int idx = lane; idx < n4; idx += 64) {
        float4 v = Fr[idx];
        s += v.x * v.x + v.y * v.y + v.z * v.z + v.w * v.w;
    }
#pragma unroll
    for (int off = 32; off > 0; off >>= 1) s += __shfl_down(s, off, 64);
    if (lane == 0) { diag[row] = s; inv_norm[row] = 1.0f / sqrtf(s); }
}

// ---------------- Gram via bf16 MFMA: Gb = bf16(Fb * Fb^T) ----------------
// 128x128 tile, 4 waves (2x2 of 64x64), BK=32, global_load_lds w/ pre-swizzled
// source, XOR-swizzled ds_read_b128 (slot ^= row&3) to cut bank conflicts.
__global__ __launch_bounds__(256) void gram_kernel(
    const unsigned short* __restrict__ Fb, unsigned short* __restrict__ Gb,
    int B, int D) {
    __shared__ unsigned short As[128 * 32];
    __shared__ unsigned short Bs[128 * 32];
    const int tid = threadIdx.x;
    const int w = tid >> 6, l = tid & 63;
    const int rowBase = blockIdx.y * 128;
    const int colBase = blockIdx.x * 128;
    const int wr = (w >> 1) * 64;
    const int wc = (w & 1) * 64;
    const int half = l >> 4;     // 16B k-slot 0..3
    const int rr   = l & 15;

    f32x4 acc[4][4];
#pragma unroll
    for (int m = 0; m < 4; ++m)
#pragma unroll
        for (int n = 0; n < 4; ++n) acc[m][n] = (f32x4){0.f, 0.f, 0.f, 0.f};

    for (int k0 = 0; k0 < D; k0 += 32) {
#pragma unroll
        for (int c = 0; c < 2; ++c) {
            const int chunk = c * 256 + w * 64 + l;   // 16B chunk id, 0..511
            const int r  = chunk >> 2;                // tile row 0..127
            const int ss = (l & 3) ^ (r & 3);         // pre-swizzled source slot
            const size_t eoff = (size_t)r * D + k0 + ss * 8;
            unsigned short* ldst = (c * 256 + w * 64) * 8 + (unsigned short*)nullptr + 0; (void)ldst;
            gload_lds16(Fb + (size_t)rowBase * D + eoff, As + (size_t)(c * 256 + w * 64) * 8);
            gload_lds16(Fb + (size_t)colBase * D + eoff, Bs + (size_t)(c * 256 + w * 64) * 8);
        }
        __syncthreads();
        bf16x8 af[4], bfr[4];
#pragma unroll
        for (int f = 0; f < 4; ++f) {
            const int ar = wr + f * 16 + rr;
            af[f]  = *(const bf16x8*)(As + ar * 32 + ((half ^ (ar & 3)) * 8));
            const int br = wc + f * 16 + rr;
            bfr[f] = *(const bf16x8*)(Bs + br * 32 + ((half ^ (br & 3)) * 8));
        }
#pragma unroll
        for (int m = 0; m < 4; ++m)
#pragma unroll
            for (int n = 0; n < 4; ++n)
                acc[m][n] = __builtin_amdgcn_mfma_f32_16x16x32_bf16(
                    af[m], bfr[n], acc[m][n], 0, 0, 0);
        __syncthreads();
    }
    // C/D layout (m91-verified): col = lane&15, row = (lane>>4)*4 + reg
#pragma unroll
    for (int m = 0; m < 4; ++m) {
        const int i0 = rowBase + wr + m * 16 + half * 4;
#pragma unroll
        for (int n = 0; n < 4; ++n) {
            const int j = colBase + wc + n * 16 + rr;
#pragma unroll
            for (int r = 0; r < 4; ++r)
                Gb[(size_t)(i0 + r) * B + j] = f2bf(acc[m][n][r]);
        }
    }
}

// ---------------- per-row contrastive + triplet ----------------
__global__ __launch_bounds__(256) void row_loss_kernel(
    const unsigned short* __restrict__ Gb, const float* __restrict__ diag,
    const float* __restrict__ inv_norm, const int* __restrict__ labels,
    float* __restrict__ accum, int B) {
    __shared__ float p_d[256];
    __shared__ float red[12];
    __shared__ int p_cnt;
    const int tid = threadIdx.x;
    const int i = blockIdx.x;
    if (tid == 0) p_cnt = 0;
    __syncthreads();

    const int   li     = labels[i];
    const float ri     = diag[i];
    const float inv_ni = inv_norm[i];
    const int   j0     = tid * 8;

    union { uint4 u; unsigned short s[8]; } GV;
    GV.u = *(const uint4*)(Gb + (size_t)i * B + j0);
    int lab[8];
    *(int4*)&lab[0] = *(const int4*)(labels + j0);
    *(int4*)&lab[4] = *(const int4*)(labels + j0 + 4);
    float dg[8], ivn[8];
    *(float4*)&dg[0]  = *(const float4*)(diag + j0);
    *(float4*)&dg[4]  = *(const float4*)(diag + j0 + 4);
    *(float4*)&ivn[0] = *(const float4*)(inv_norm + j0);
    *(float4*)&ivn[4] = *(const float4*)(inv_norm + j0 + 4);

    float pos = 0.0f, neg = 0.0f;
    float d8[8];
    int mmask = 0;
#pragma unroll
    for (int e = 0; e < 8; ++e) {
        const int j = j0 + e;
        const float g = bf2f(GV.s[e]);
        float sim = g * inv_ni * ivn[e];
        const float d2 = ri - 2.0f * g + dg[e];
        float d = (d2 > 0.0f) ? sqrtf(d2) : 0.0f;
        if (j == i) { sim = 1.0f; d = 0.0f; }   // diagonal exact
        d8[e] = d;
        if (lab[e] == li) {
            pos += -logf(expf(sim * TEMP_INV) + 1e-8f);
            neg += C_MARGIN;                     // relu(0.5 - 0)
            mmask |= (1 << e);
            int slot = atomicAdd(&p_cnt, 1);
            if (slot < 256) p_d[slot] = d;
        } else {
            // pos term: -log(exp(0)+1e-8) == -log(1) == 0 in fp32 (matches ref)
            neg += fmaxf(C_MARGIN - sim, 0.0f);
        }
    }
    __syncthreads();
    const int cnt = (p_cnt < 256) ? p_cnt : 256;
    float trip = 0.0f;
    for (int p = 0; p < cnt; ++p) {
        const float dp = p_d[p] + T_MARGIN;
#pragma unroll
        for (int e = 0; e < 8; ++e)
            if (!(mmask & (1 << e))) trip += fmaxf(dp - d8[e], 0.0f);
    }

    float r0 = pos, r1 = neg, r2 = trip;
#pragma unroll
    for (int off = 32; off > 0; off >>= 1) {
        r0 += __shfl_down(r0, off, 64);
        r1 += __shfl_down(r1, off, 64);
        r2 += __shfl_down(r2, off, 64);
    }
    const int lane = tid & 63, wid = tid >> 6;
    if (lane == 0) { red[wid] = r0; red[4 + wid] = r1; red[8 + wid] = r2; }
    __syncthreads();
    if (tid == 0) {
        atomicAdd(&accum[0], red[0] + red[1] + red[2] + red[3]);
        atomicAdd(&accum[1], red[4] + red[5] + red[6] + red[7]);
        atomicAdd(&accum[2], red[8] + red[9] + red[10] + red[11]);
    }
}

// ---------------- focal + label smoothing, single pass ----------------
__global__ __launch_bounds__(256) void ce_kernel(
    const float* __restrict__ pred, const int* __restrict__ target,
    float* __restrict__ accum, int C, float off_const) {
    __shared__ float redm[4], reds[4], redp[4];
    const int i = blockIdx.x, tid = threadIdx.x;
    const float* row = pred + (size_t)i * C;
    const int Cv = C >> 2;

    float m = -1e30f, s = 0.0f, sp = 0.0f;
    for (int idx = tid; idx < Cv; idx += 256) {
        float4 v = ((const float4*)row)[idx];
        float mv = fmaxf(fmaxf(v.x, v.y), fmaxf(v.z, v.w));
        if (mv > m) { s *= expf(m - mv); m = mv; }
        s += expf(v.x - m) + expf(v.y - m) + expf(v.z - m) + expf(v.w - m);
        sp += v.x + v.y + v.z + v.w;
    }
    for (int j = Cv * 4 + tid; j < C; j += 256) {   // tail (none for C=1000)
        float v = row[j];
        if (v > m) { s *= expf(m - v); m = v; }
        s += expf(v - m);
        sp += v;
    }
#pragma unroll
    for (int off = 32; off > 0; off >>= 1) {
        float mo = __shfl_down(m, off, 64);
        float so = __shfl_down(s, off, 64);
        sp += __shfl_down(sp, off, 64);
        float mm = fmaxf(m, mo);
        s = s * expf(m - mm) + so * expf(mo - mm);
        m = mm;
    }
    if ((tid & 63) == 0) { redm[tid >> 6] = m; reds[tid >> 6] = s; redp[tid >> 6] = sp; }
    __syncthreads();
    if (tid == 0) {
        float mm = redm[0], ss = reds[0], spT = redp[0];
#pragma unroll
        for (int q = 1; q < 4; ++q) {
            float mo = redm[q], so = reds[q];
            float mn = fmaxf(mm, mo);
            ss = ss * expf(mm - mn) + so * expf(mo - mn);
            mm = mn;
            spT += redp[q];
        }
        float lse = mm + logf(ss);
        float tl  = row[target[i]] - lse;
        float ce  = -tl;
        float pt  = expf(tl);
        float omp = 1.0f - pt;
        float focal = ALPHA * omp * omp * ce;
        float sumlogp = spT - (float)C * lse;
        float lsv = -(off_const * sumlogp + ((1.0f - SMOOTHING) - off_const) * tl);
        atomicAdd(&accum[3], focal);
        atomicAdd(&accum[4], lsv);
    }
}

// ---------------- combine ----------------
__global__ void combine_kernel(const float* __restrict__ accum,
                               float* __restrict__ out, int B) {
    if (threadIdx.x == 0 && blockIdx.x == 0) {
        double invB2 = 1.0 / ((double)B * (double)B);
        float lc = (float)(((double)accum[0] + (double)accum[1]) * invB2);
        float lt = (float)((double)accum[2] / ((double)B + 1e-8));
        float lf = accum[3] / (float)B;
        float ls = accum[4] / (float)B;
        out[0] = lc;
        out[1] = lt;
        out[2] = lf;
        out[3] = ls;
        out[4] = 0.1f * lc + 0.1f * lt + 0.4f * lf + 0.4f * ls;
    }
}

// ---------------- launch ----------------
extern "C" void kernel_launch(void* const* d_in, const int* in_sizes, int n_in,
                              void* d_out, int out_size, void* d_ws, size_t ws_size,
                              hipStream_t stream) {
    const float* pred     = (const float*)d_in[0];
    const int*   target   = (const int*)d_in[1];
    const float* features = (const float*)d_in[2];
    const int B = in_sizes[1];
    const int C = in_sizes[0] / B;
    const int D = in_sizes[2] / B;
    float* out = (float*)d_out;

    // workspace layout (total ~10.7 MB for B=2048, D=512)
    float* accum    = (float*)d_ws;                 // 64 floats
    float* diag     = accum + 64;                   // B
    float* inv_norm = diag + B;                     // B
    unsigned short* Fb = (unsigned short*)(inv_norm + B);   // B*D bf16 (16B-aligned)
    unsigned short* Gb = Fb + (size_t)B * D;                // B*B bf16

    init_accum_kernel<<<1, 64, 0, stream>>>(accum);

    int n4 = (B * D) >> 2;
    cvt_kernel<<<(n4 + 255) / 256, 256, 0, stream>>>(features, Fb, n4);

    norms_kernel<<<B / 4, 256, 0, stream>>>(features, diag, inv_norm, D);

    dim3 ggrid(B / 128, B / 128);
    gram_kernel<<<ggrid, 256, 0, stream>>>(Fb, Gb, B, D);

    row_loss_kernel<<<B, 256, 0, stream>>>(Gb, diag, inv_norm, target, accum, B);

    float off_const = SMOOTHING / (float)(C - 1);
    ce_kernel<<<B, 256, 0, stream>>>(pred, target, accum, C, off_const);

    combine_kernel<<<1, 1, 0, stream>>>(accum, out, B);
}

// Round 3
// 43.252 us; speedup vs baseline: 5.3179x; 3.9116x over previous
//
#include <hip/hip_runtime.h>
#include <hip/hip_bf16.h>
#include <math.h>

typedef __attribute__((ext_vector_type(8))) short bf16x8;
typedef __attribute__((ext_vector_type(4))) float f32x4;

static constexpr float TEMP_INV  = 1.0f / 0.07f;
static constexpr float C_MARGIN  = 0.5f;
static constexpr float T_MARGIN  = 1.0f;
static constexpr float ALPHA     = 0.25f;
static constexpr float SMOOTHING = 0.1f;

__device__ __forceinline__ void gload_lds16(const void* g, void* l) {
    __builtin_amdgcn_global_load_lds(
        (const __attribute__((address_space(1))) void*)g,
        (__attribute__((address_space(3))) void*)l,
        16, 0, 0);
}

__device__ __forceinline__ unsigned short f2bf(float x) {
    __hip_bfloat16 h = __float2bfloat16(x);   // RNE
    return *reinterpret_cast<unsigned short*>(&h);
}
__device__ __forceinline__ float bf2f(unsigned short u) {
    union { unsigned int u32; float f; } U;
    U.u32 = ((unsigned int)u) << 16;
    return U.f;
}

// ---------------- fused: F->bf16 + exact fp32 row norms (one wave/row) ------
__global__ __launch_bounds__(256) void prep_kernel(
    const float* __restrict__ F, unsigned short* __restrict__ Fb,
    float* __restrict__ diag, float* __restrict__ inv_norm, int D) {
    const int row  = blockIdx.x * 4 + (threadIdx.x >> 6);
    const int lane = threadIdx.x & 63;
    const float4* Fr  = (const float4*)(F + (size_t)row * D);
    ushort4*      Fbr = (ushort4*)(Fb + (size_t)row * D);
    const int n4 = D >> 2;
    float s = 0.0f;
    for (int idx = lane; idx < n4; idx += 64) {
        float4 v = Fr[idx];
        s += v.x * v.x + v.y * v.y + v.z * v.z + v.w * v.w;
        ushort4 o;
        o.x = f2bf(v.x); o.y = f2bf(v.y); o.z = f2bf(v.z); o.w = f2bf(v.w);
        Fbr[idx] = o;
    }
#pragma unroll
    for (int off = 32; off > 0; off >>= 1) s += __shfl_down(s, off, 64);
    if (lane == 0) { diag[row] = s; inv_norm[row] = 1.0f / sqrtf(s); }
}

// ---------------- Gram via bf16 MFMA: Gb = bf16(Fb * Fb^T) ----------------
__global__ __launch_bounds__(256) void gram_kernel(
    const unsigned short* __restrict__ Fb, unsigned short* __restrict__ Gb,
    int B, int D) {
    __shared__ unsigned short As[128 * 32];
    __shared__ unsigned short Bs[128 * 32];
    const int tid = threadIdx.x;
    const int w = tid >> 6, l = tid & 63;
    const int rowBase = blockIdx.y * 128;
    const int colBase = blockIdx.x * 128;
    const int wr = (w >> 1) * 64;
    const int wc = (w & 1) * 64;
    const int half = l >> 4;     // 16B k-slot 0..3
    const int rr   = l & 15;

    f32x4 acc[4][4];
#pragma unroll
    for (int m = 0; m < 4; ++m)
#pragma unroll
        for (int n = 0; n < 4; ++n) acc[m][n] = (f32x4){0.f, 0.f, 0.f, 0.f};

    for (int k0 = 0; k0 < D; k0 += 32) {
#pragma unroll
        for (int c = 0; c < 2; ++c) {
            const int chunk = c * 256 + w * 64 + l;   // 16B chunk id, 0..511
            const int r  = chunk >> 2;                // tile row 0..127
            const int ss = (l & 3) ^ (r & 3);         // pre-swizzled source slot
            const size_t eoff = (size_t)r * D + k0 + ss * 8;
            gload_lds16(Fb + (size_t)rowBase * D + eoff, As + (size_t)(c * 256 + w * 64) * 8);
            gload_lds16(Fb + (size_t)colBase * D + eoff, Bs + (size_t)(c * 256 + w * 64) * 8);
        }
        __syncthreads();
        bf16x8 af[4], bfr[4];
#pragma unroll
        for (int f = 0; f < 4; ++f) {
            const int ar = wr + f * 16 + rr;
            af[f]  = *(const bf16x8*)(As + ar * 32 + ((half ^ (ar & 3)) * 8));
            const int br = wc + f * 16 + rr;
            bfr[f] = *(const bf16x8*)(Bs + br * 32 + ((half ^ (br & 3)) * 8));
        }
#pragma unroll
        for (int m = 0; m < 4; ++m)
#pragma unroll
            for (int n = 0; n < 4; ++n)
                acc[m][n] = __builtin_amdgcn_mfma_f32_16x16x32_bf16(
                    af[m], bfr[n], acc[m][n], 0, 0, 0);
        __syncthreads();
    }
    // C/D layout (m91-verified): col = lane&15, row = (lane>>4)*4 + reg
#pragma unroll
    for (int m = 0; m < 4; ++m) {
        const int i0 = rowBase + wr + m * 16 + half * 4;
#pragma unroll
        for (int n = 0; n < 4; ++n) {
            const int j = colBase + wc + n * 16 + rr;
#pragma unroll
            for (int r = 0; r < 4; ++r)
                Gb[(size_t)(i0 + r) * B + j] = f2bf(acc[m][n][r]);
        }
    }
}

// ---------------- per-row contrastive + triplet -> partial[i*8+{0,1,2}] ----
__global__ __launch_bounds__(256) void row_loss_kernel(
    const unsigned short* __restrict__ Gb, const float* __restrict__ diag,
    const float* __restrict__ inv_norm, const int* __restrict__ labels,
    float* __restrict__ partial, int B) {
    __shared__ float p_d[256];
    __shared__ float red[12];
    __shared__ int p_cnt;
    const int tid = threadIdx.x;
    const int i = blockIdx.x;
    if (tid == 0) p_cnt = 0;
    __syncthreads();

    const int   li     = labels[i];
    const float ri     = diag[i];
    const float inv_ni = inv_norm[i];
    const int   j0     = tid * 8;

    union { uint4 u; unsigned short s[8]; } GV;
    GV.u = *(const uint4*)(Gb + (size_t)i * B + j0);
    int lab[8];
    *(int4*)&lab[0] = *(const int4*)(labels + j0);
    *(int4*)&lab[4] = *(const int4*)(labels + j0 + 4);
    float dg[8], ivn[8];
    *(float4*)&dg[0]  = *(const float4*)(diag + j0);
    *(float4*)&dg[4]  = *(const float4*)(diag + j0 + 4);
    *(float4*)&ivn[0] = *(const float4*)(inv_norm + j0);
    *(float4*)&ivn[4] = *(const float4*)(inv_norm + j0 + 4);

    float pos = 0.0f, neg = 0.0f;
    float d8[8];
    int mmask = 0;
#pragma unroll
    for (int e = 0; e < 8; ++e) {
        const int j = j0 + e;
        const float g = bf2f(GV.s[e]);
        float sim = g * inv_ni * ivn[e];
        const float d2 = ri - 2.0f * g + dg[e];
        float d = (d2 > 0.0f) ? sqrtf(d2) : 0.0f;
        if (j == i) { sim = 1.0f; d = 0.0f; }   // diagonal exact
        d8[e] = d;
        if (lab[e] == li) {
            pos += -logf(expf(sim * TEMP_INV) + 1e-8f);
            neg += C_MARGIN;                     // relu(0.5 - 0)
            mmask |= (1 << e);
            int slot = atomicAdd(&p_cnt, 1);
            if (slot < 256) p_d[slot] = d;
        } else {
            // pos term: -log(exp(0)+1e-8) == 0 in fp32 (matches ref)
            neg += fmaxf(C_MARGIN - sim, 0.0f);
        }
    }
    __syncthreads();
    const int cnt = (p_cnt < 256) ? p_cnt : 256;
    float trip = 0.0f;
    for (int p = 0; p < cnt; ++p) {
        const float dp = p_d[p] + T_MARGIN;
#pragma unroll
        for (int e = 0; e < 8; ++e)
            if (!(mmask & (1 << e))) trip += fmaxf(dp - d8[e], 0.0f);
    }

    float r0 = pos, r1 = neg, r2 = trip;
#pragma unroll
    for (int off = 32; off > 0; off >>= 1) {
        r0 += __shfl_down(r0, off, 64);
        r1 += __shfl_down(r1, off, 64);
        r2 += __shfl_down(r2, off, 64);
    }
    const int lane = tid & 63, wid = tid >> 6;
    if (lane == 0) { red[wid] = r0; red[4 + wid] = r1; red[8 + wid] = r2; }
    __syncthreads();
    if (tid == 0) {
        float* p = partial + (size_t)i * 8;
        p[0] = red[0] + red[1] + red[2] + red[3];
        p[1] = red[4] + red[5] + red[6] + red[7];
        p[2] = red[8] + red[9] + red[10] + red[11];
    }
}

// ---------------- focal + label smoothing -> partial[i*8+{3,4}] ----------
__global__ __launch_bounds__(256) void ce_kernel(
    const float* __restrict__ pred, const int* __restrict__ target,
    float* __restrict__ partial, int C, float off_const) {
    __shared__ float redm[4], reds[4], redp[4];
    const int i = blockIdx.x, tid = threadIdx.x;
    const float* row = pred + (size_t)i * C;
    const int Cv = C >> 2;

    float m = -1e30f, s = 0.0f, sp = 0.0f;
    for (int idx = tid; idx < Cv; idx += 256) {
        float4 v = ((const float4*)row)[idx];
        float mv = fmaxf(fmaxf(v.x, v.y), fmaxf(v.z, v.w));
        if (mv > m) { s *= expf(m - mv); m = mv; }
        s += expf(v.x - m) + expf(v.y - m) + expf(v.z - m) + expf(v.w - m);
        sp += v.x + v.y + v.z + v.w;
    }
    for (int j = Cv * 4 + tid; j < C; j += 256) {   // tail (none for C=1000)
        float v = row[j];
        if (v > m) { s *= expf(m - v); m = v; }
        s += expf(v - m);
        sp += v;
    }
#pragma unroll
    for (int off = 32; off > 0; off >>= 1) {
        float mo = __shfl_down(m, off, 64);
        float so = __shfl_down(s, off, 64);
        sp += __shfl_down(sp, off, 64);
        float mm = fmaxf(m, mo);
        s = s * expf(m - mm) + so * expf(mo - mm);
        m = mm;
    }
    if ((tid & 63) == 0) { redm[tid >> 6] = m; reds[tid >> 6] = s; redp[tid >> 6] = sp; }
    __syncthreads();
    if (tid == 0) {
        float mm = redm[0], ss = reds[0], spT = redp[0];
#pragma unroll
        for (int q = 1; q < 4; ++q) {
            float mo = redm[q], so = reds[q];
            float mn = fmaxf(mm, mo);
            ss = ss * expf(mm - mn) + so * expf(mo - mn);
            mm = mn;
            spT += redp[q];
        }
        float lse = mm + logf(ss);
        float tl  = row[target[i]] - lse;
        float ce  = -tl;
        float pt  = expf(tl);
        float omp = 1.0f - pt;
        float focal = ALPHA * omp * omp * ce;
        float sumlogp = spT - (float)C * lse;
        float lsv = -(off_const * sumlogp + ((1.0f - SMOOTHING) - off_const) * tl);
        float* p = partial + (size_t)i * 8;
        p[3] = focal;
        p[4] = lsv;
    }
}

// ---------------- final reduce over B rows x 5 components ----------------
__global__ __launch_bounds__(256) void reduce_kernel(
    const float* __restrict__ partial, float* __restrict__ out, int B) {
    __shared__ float red[4][5];
    const int tid = threadIdx.x;
    float s[5] = {0.f, 0.f, 0.f, 0.f, 0.f};
    for (int r = tid; r < B; r += 256) {
        float4 p0 = *(const float4*)(partial + (size_t)r * 8);
        float  p4 = partial[(size_t)r * 8 + 4];
        s[0] += p0.x; s[1] += p0.y; s[2] += p0.z; s[3] += p0.w; s[4] += p4;
    }
#pragma unroll
    for (int off = 32; off > 0; off >>= 1) {
#pragma unroll
        for (int k = 0; k < 5; ++k) s[k] += __shfl_down(s[k], off, 64);
    }
    const int lane = tid & 63, wid = tid >> 6;
    if (lane == 0) {
#pragma unroll
        for (int k = 0; k < 5; ++k) red[wid][k] = s[k];
    }
    __syncthreads();
    if (tid == 0) {
        float t[5];
#pragma unroll
        for (int k = 0; k < 5; ++k)
            t[k] = red[0][k] + red[1][k] + red[2][k] + red[3][k];
        double invB2 = 1.0 / ((double)B * (double)B);
        float lc = (float)(((double)t[0] + (double)t[1]) * invB2);
        float lt = (float)((double)t[2] / ((double)B + 1e-8));
        float lf = t[3] / (float)B;
        float ls = t[4] / (float)B;
        out[0] = lc;
        out[1] = lt;
        out[2] = lf;
        out[3] = ls;
        out[4] = 0.1f * lc + 0.1f * lt + 0.4f * lf + 0.4f * ls;
    }
}

// ---------------- launch ----------------
extern "C" void kernel_launch(void* const* d_in, const int* in_sizes, int n_in,
                              void* d_out, int out_size, void* d_ws, size_t ws_size,
                              hipStream_t stream) {
    const float* pred     = (const float*)d_in[0];
    const int*   target   = (const int*)d_in[1];
    const float* features = (const float*)d_in[2];
    const int B = in_sizes[1];
    const int C = in_sizes[0] / B;
    const int D = in_sizes[2] / B;
    float* out = (float*)d_out;

    // workspace layout (~12.8 MB for B=2048, D=512)
    float* partial  = (float*)d_ws;                      // B*8 floats (64 KB)
    float* diag     = partial + (size_t)B * 8;           // B
    float* inv_norm = diag + B;                          // B
    unsigned short* Fb = (unsigned short*)(inv_norm + B);   // B*D bf16
    unsigned short* Gb = Fb + (size_t)B * D;                // B*B bf16

    prep_kernel<<<B / 4, 256, 0, stream>>>(features, Fb, diag, inv_norm, D);

    dim3 ggrid(B / 128, B / 128);
    gram_kernel<<<ggrid, 256, 0, stream>>>(Fb, Gb, B, D);

    row_loss_kernel<<<B, 256, 0, stream>>>(Gb, diag, inv_norm, target, partial, B);

    float off_const = SMOOTHING / (float)(C - 1);
    ce_kernel<<<B, 256, 0, stream>>>(pred, target, partial, C, off_const);

    reduce_kernel<<<1, 256, 0, stream>>>(partial, out, B);
}

// Round 4
// 41.202 us; speedup vs baseline: 5.5826x; 1.0498x over previous
//
#include <hip/hip_runtime.h>
#include <hip/hip_bf16.h>
#include <math.h>

typedef __attribute__((ext_vector_type(8))) short bf16x8;
typedef __attribute__((ext_vector_type(4))) float f32x4;

static constexpr float TEMP_INV  = 1.0f / 0.07f;
static constexpr float C_MARGIN  = 0.5f;
static constexpr float T_MARGIN  = 1.0f;
static constexpr float ALPHA     = 0.25f;
static constexpr float SMOOTHING = 0.1f;

__device__ __forceinline__ void gload_lds16(const void* g, void* l) {
    __builtin_amdgcn_global_load_lds(
        (const __attribute__((address_space(1))) void*)g,
        (__attribute__((address_space(3))) void*)l,
        16, 0, 0);
}

__device__ __forceinline__ unsigned short f2bf(float x) {
    __hip_bfloat16 h = __float2bfloat16(x);   // RNE
    return *reinterpret_cast<unsigned short*>(&h);
}
__device__ __forceinline__ float bf2f(unsigned short u) {
    union { unsigned int u32; float f; } U;
    U.u32 = ((unsigned int)u) << 16;
    return U.f;
}

// ---------------- fused: F->bf16 + exact fp32 row norms (one wave/row) ------
__global__ __launch_bounds__(256) void prep_kernel(
    const float* __restrict__ F, unsigned short* __restrict__ Fb,
    float* __restrict__ diag, float* __restrict__ inv_norm, int D) {
    const int row  = blockIdx.x * 4 + (threadIdx.x >> 6);
    const int lane = threadIdx.x & 63;
    const float4* Fr  = (const float4*)(F + (size_t)row * D);
    ushort4*      Fbr = (ushort4*)(Fb + (size_t)row * D);
    const int n4 = D >> 2;
    float s = 0.0f;
    for (int idx = lane; idx < n4; idx += 64) {
        float4 v = Fr[idx];
        s += v.x * v.x + v.y * v.y + v.z * v.z + v.w * v.w;
        ushort4 o;
        o.x = f2bf(v.x); o.y = f2bf(v.y); o.z = f2bf(v.z); o.w = f2bf(v.w);
        Fbr[idx] = o;
    }
#pragma unroll
    for (int off = 32; off > 0; off >>= 1) s += __shfl_down(s, off, 64);
    if (lane == 0) { diag[row] = s; inv_norm[row] = 1.0f / sqrtf(s); }
}

// ---------------- Gram via bf16 MFMA, 2-phase double-buffered LDS ----------
// 128x128 tile, 4 waves (2x2 of 64x64), BK=32. STAGE(next) issued before
// compute(cur); single __syncthreads per K-step drains vmcnt AFTER the MFMAs,
// so global->LDS staging overlaps compute (T3-minimum template).
__global__ __launch_bounds__(256) void gram_kernel(
    const unsigned short* __restrict__ Fb, unsigned short* __restrict__ Gb,
    int B, int D) {
    __shared__ unsigned short As[2][128 * 32];
    __shared__ unsigned short Bs[2][128 * 32];
    const int tid = threadIdx.x;
    const int w = tid >> 6, l = tid & 63;
    const int rowBase = blockIdx.y * 128;
    const int colBase = blockIdx.x * 128;
    const int wr = (w >> 1) * 64;
    const int wc = (w & 1) * 64;
    const int half = l >> 4;     // 16B k-slot 0..3
    const int rr   = l & 15;

    const unsigned short* FA = Fb + (size_t)rowBase * D;
    const unsigned short* FB = Fb + (size_t)colBase * D;

    f32x4 acc[4][4];
#pragma unroll
    for (int m = 0; m < 4; ++m)
#pragma unroll
        for (int n = 0; n < 4; ++n) acc[m][n] = (f32x4){0.f, 0.f, 0.f, 0.f};

    auto stage = [&](int buf, int k0) {
#pragma unroll
        for (int c = 0; c < 2; ++c) {
            const int chunk = c * 256 + w * 64 + l;   // 16B chunk id, 0..511
            const int r2 = chunk >> 2;                // tile row 0..127
            const int ss = (l & 3) ^ (r2 & 3);        // pre-swizzled source slot
            const size_t eoff = (size_t)r2 * D + k0 + ss * 8;
            gload_lds16(FA + eoff, &As[buf][(c * 256 + w * 64) * 8]);
            gload_lds16(FB + eoff, &Bs[buf][(c * 256 + w * 64) * 8]);
        }
    };

    const int NT = D / 32;
    stage(0, 0);
    __syncthreads();                       // prologue drain: buf0 ready
    int cur = 0;
    for (int t = 0; t < NT; ++t) {
        if (t + 1 < NT) stage(cur ^ 1, (t + 1) * 32);   // fly under compute
        bf16x8 af[4], bfv[4];
#pragma unroll
        for (int f = 0; f < 4; ++f) {
            const int ar = wr + f * 16 + rr;
            af[f]  = *(const bf16x8*)(&As[cur][ar * 32 + ((half ^ (ar & 3)) * 8)]);
            const int br = wc + f * 16 + rr;
            bfv[f] = *(const bf16x8*)(&Bs[cur][br * 32 + ((half ^ (br & 3)) * 8)]);
        }
#pragma unroll
        for (int m = 0; m < 4; ++m)
#pragma unroll
            for (int n = 0; n < 4; ++n)
                acc[m][n] = __builtin_amdgcn_mfma_f32_16x16x32_bf16(
                    af[m], bfv[n], acc[m][n], 0, 0, 0);
        __syncthreads();                   // vmcnt(0)+barrier: next buf ready,
        cur ^= 1;                          // cur free to overwrite
    }
    // C/D layout (m91-verified): col = lane&15, row = (lane>>4)*4 + reg
#pragma unroll
    for (int m = 0; m < 4; ++m) {
        const int i0 = rowBase + wr + m * 16 + half * 4;
#pragma unroll
        for (int n = 0; n < 4; ++n) {
            const int j = colBase + wc + n * 16 + rr;
#pragma unroll
            for (int r = 0; r < 4; ++r)
                Gb[(size_t)(i0 + r) * B + j] = f2bf(acc[m][n][r]);
        }
    }
}

// ---- fused per-row: contrastive + triplet + focal + label-smooth ----------
// One block per row. pred loads issued at entry so HBM latency hides under
// phase A (T14 issue-early). Writes partial[i*8 + {0..4}], no global atomics.
__global__ __launch_bounds__(256) void row_ce_kernel(
    const unsigned short* __restrict__ Gb, const float* __restrict__ diag,
    const float* __restrict__ inv_norm, const int* __restrict__ labels,
    const float* __restrict__ pred, const int* __restrict__ target,
    float* __restrict__ partial, int B, int C, float off_const) {
    __shared__ float p_d[256];
    __shared__ float red[12];
    __shared__ float redm[4], reds[4], redp[4];
    __shared__ int p_cnt;
    const int tid = threadIdx.x;
    const int i = blockIdx.x;

    // ---- phase B data: issue loads NOW, consume after phase A ----
    const float* prow = pred + (size_t)i * C;
    const int Cv = C >> 2;
    float4 pv = make_float4(0.f, 0.f, 0.f, 0.f);
    if (tid < Cv) pv = ((const float4*)prow)[tid];
    const float tlogit = prow[target[i]];

    if (tid == 0) p_cnt = 0;
    __syncthreads();

    // ---------------- phase A: contrastive + triplet ----------------
    const int   li     = labels[i];
    const float ri     = diag[i];
    const float inv_ni = inv_norm[i];
    const int   j0     = tid * 8;

    union { uint4 u; unsigned short s[8]; } GV;
    GV.u = *(const uint4*)(Gb + (size_t)i * B + j0);
    int lab[8];
    *(int4*)&lab[0] = *(const int4*)(labels + j0);
    *(int4*)&lab[4] = *(const int4*)(labels + j0 + 4);
    float dg[8], ivn[8];
    *(float4*)&dg[0]  = *(const float4*)(diag + j0);
    *(float4*)&dg[4]  = *(const float4*)(diag + j0 + 4);
    *(float4*)&ivn[0] = *(const float4*)(inv_norm + j0);
    *(float4*)&ivn[4] = *(const float4*)(inv_norm + j0 + 4);

    float pos = 0.0f, neg = 0.0f;
    float d8[8];
    int mmask = 0;
#pragma unroll
    for (int e = 0; e < 8; ++e) {
        const int j = j0 + e;
        const float g = bf2f(GV.s[e]);
        float sim = g * inv_ni * ivn[e];
        const float d2 = ri - 2.0f * g + dg[e];
        float d = (d2 > 0.0f) ? sqrtf(d2) : 0.0f;
        if (j == i) { sim = 1.0f; d = 0.0f; }   // diagonal exact
        d8[e] = d;
        if (lab[e] == li) {
            pos += -logf(expf(sim * TEMP_INV) + 1e-8f);
            neg += C_MARGIN;                     // relu(0.5 - 0)
            mmask |= (1 << e);
            int slot = atomicAdd(&p_cnt, 1);
            if (slot < 256) p_d[slot] = d;
        } else {
            // pos term: -log(exp(0)+1e-8) == 0 in fp32 (matches ref)
            neg += fmaxf(C_MARGIN - sim, 0.0f);
        }
    }
    __syncthreads();
    const int cnt = (p_cnt < 256) ? p_cnt : 256;
    float trip = 0.0f;
    for (int p = 0; p < cnt; ++p) {
        const float dp = p_d[p] + T_MARGIN;
#pragma unroll
        for (int e = 0; e < 8; ++e)
            if (!(mmask & (1 << e))) trip += fmaxf(dp - d8[e], 0.0f);
    }

    float r0 = pos, r1 = neg, r2 = trip;
#pragma unroll
    for (int off = 32; off > 0; off >>= 1) {
        r0 += __shfl_down(r0, off, 64);
        r1 += __shfl_down(r1, off, 64);
        r2 += __shfl_down(r2, off, 64);
    }
    const int lane = tid & 63, wid = tid >> 6;
    if (lane == 0) { red[wid] = r0; red[4 + wid] = r1; red[8 + wid] = r2; }

    // ---------------- phase B: focal + label smoothing ----------------
    float m = -1e30f, s = 0.0f, sp = 0.0f;
    if (tid < Cv) {
        m  = fmaxf(fmaxf(pv.x, pv.y), fmaxf(pv.z, pv.w));
        s  = expf(pv.x - m) + expf(pv.y - m) + expf(pv.z - m) + expf(pv.w - m);
        sp = pv.x + pv.y + pv.z + pv.w;
    }
    for (int idx = 256 + tid; idx < Cv; idx += 256) {   // none for C=1000
        float4 v = ((const float4*)prow)[idx];
        float mv = fmaxf(fmaxf(v.x, v.y), fmaxf(v.z, v.w));
        if (mv > m) { s *= expf(m - mv); m = mv; }
        s += expf(v.x - m) + expf(v.y - m) + expf(v.z - m) + expf(v.w - m);
        sp += v.x + v.y + v.z + v.w;
    }
    for (int j = Cv * 4 + tid; j < C; j += 256) {       // scalar tail
        float v = prow[j];
        if (v > m) { s *= expf(m - v); m = v; }
        s += expf(v - m);
        sp += v;
    }
#pragma unroll
    for (int off = 32; off > 0; off >>= 1) {
        float mo = __shfl_down(m, off, 64);
        float so = __shfl_down(s, off, 64);
        sp += __shfl_down(sp, off, 64);
        float mx = fmaxf(m, mo);
        s = s * expf(m - mx) + so * expf(mo - mx);
        m = mx;
    }
    if (lane == 0) { redm[wid] = m; reds[wid] = s; redp[wid] = sp; }
    __syncthreads();

    if (tid == 0) {
        // phase A totals
        float t0 = red[0] + red[1] + red[2] + red[3];
        float t1 = red[4] + red[5] + red[6] + red[7];
        float t2 = red[8] + red[9] + red[10] + red[11];
        // phase B online combine across 4 waves
        float mm = redm[0], ss = reds[0], spT = redp[0];
#pragma unroll
        for (int q = 1; q < 4; ++q) {
            float mo = redm[q], so = reds[q];
            float mn = fmaxf(mm, mo);
            ss = ss * expf(mm - mn) + so * expf(mo - mn);
            mm = mn;
            spT += redp[q];
        }
        float lse = mm + logf(ss);
        float tl  = tlogit - lse;
        float ce  = -tl;
        float pt  = expf(tl);
        float omp = 1.0f - pt;
        float focal = ALPHA * omp * omp * ce;           // gamma = 2
        float sumlogp = spT - (float)C * lse;
        float lsv = -(off_const * sumlogp + ((1.0f - SMOOTHING) - off_const) * tl);
        float* p = partial + (size_t)i * 8;
        p[0] = t0; p[1] = t1; p[2] = t2; p[3] = focal; p[4] = lsv;
    }
}

// ---------------- final reduce over B rows x 5 components ----------------
__global__ __launch_bounds__(256) void reduce_kernel(
    const float* __restrict__ partial, float* __restrict__ out, int B) {
    __shared__ float red[4][5];
    const int tid = threadIdx.x;
    float s[5] = {0.f, 0.f, 0.f, 0.f, 0.f};
    for (int r = tid; r < B; r += 256) {
        float4 p0 = *(const float4*)(partial + (size_t)r * 8);
        float  p4 = partial[(size_t)r * 8 + 4];
        s[0] += p0.x; s[1] += p0.y; s[2] += p0.z; s[3] += p0.w; s[4] += p4;
    }
#pragma unroll
    for (int off = 32; off > 0; off >>= 1) {
#pragma unroll
        for (int k = 0; k < 5; ++k) s[k] += __shfl_down(s[k], off, 64);
    }
    const int lane = tid & 63, wid = tid >> 6;
    if (lane == 0) {
#pragma unroll
        for (int k = 0; k < 5; ++k) red[wid][k] = s[k];
    }
    __syncthreads();
    if (tid == 0) {
        float t[5];
#pragma unroll
        for (int k = 0; k < 5; ++k)
            t[k] = red[0][k] + red[1][k] + red[2][k] + red[3][k];
        double invB2 = 1.0 / ((double)B * (double)B);
        float lc = (float)(((double)t[0] + (double)t[1]) * invB2);
        float lt = (float)((double)t[2] / ((double)B + 1e-8));
        float lf = t[3] / (float)B;
        float ls = t[4] / (float)B;
        out[0] = lc;
        out[1] = lt;
        out[2] = lf;
        out[3] = ls;
        out[4] = 0.1f * lc + 0.1f * lt + 0.4f * lf + 0.4f * ls;
    }
}

// ---------------- launch ----------------
extern "C" void kernel_launch(void* const* d_in, const int* in_sizes, int n_in,
                              void* d_out, int out_size, void* d_ws, size_t ws_size,
                              hipStream_t stream) {
    const float* pred     = (const float*)d_in[0];
    const int*   target   = (const int*)d_in[1];
    const float* features = (const float*)d_in[2];
    const int B = in_sizes[1];
    const int C = in_sizes[0] / B;
    const int D = in_sizes[2] / B;
    float* out = (float*)d_out;

    // workspace layout (~12.8 MB for B=2048, D=512)
    float* partial  = (float*)d_ws;                      // B*8 floats (64 KB)
    float* diag     = partial + (size_t)B * 8;           // B
    float* inv_norm = diag + B;                          // B
    unsigned short* Fb = (unsigned short*)(inv_norm + B);   // B*D bf16
    unsigned short* Gb = Fb + (size_t)B * D;                // B*B bf16

    prep_kernel<<<B / 4, 256, 0, stream>>>(features, Fb, diag, inv_norm, D);

    dim3 ggrid(B / 128, B / 128);
    gram_kernel<<<ggrid, 256, 0, stream>>>(Fb, Gb, B, D);

    float off_const = SMOOTHING / (float)(C - 1);
    row_ce_kernel<<<B, 256, 0, stream>>>(Gb, diag, inv_norm, target,
                                         pred, target, partial, B, C, off_const);

    reduce_kernel<<<1, 256, 0, stream>>>(partial, out, B);
}